// Round 6
// baseline (4912.819 us; speedup 1.0000x reference)
//
#include <hip/hip_runtime.h>

typedef _Float16 half8 __attribute__((ext_vector_type(8)));
typedef float f32x4 __attribute__((ext_vector_type(4)));

#define TT   512
#define BB   16      // batch cols per pair
#define HH   50
#define NTHR 512     // 8 waves per block
#define NPAIR 256
#define L2E  1.44269504088896340736f

__device__ __forceinline__ float rcp_f(float x) { return __builtin_amdgcn_rcpf(x); }
__device__ __forceinline__ float exp2_f(float x) { return __builtin_amdgcn_exp2f(x); }

// Fused LSTM cell update (preacts prescaled: i,f,o by -log2e; g by +2log2e)
__device__ __forceinline__ float cell_update(f32x4 a, float& c) {
    float ei = exp2_f(a[0]);
    float ef = exp2_f(a[1]);
    float eg = exp2_f(a[2]);
    float eo = exp2_f(a[3]);
    float A  = 1.0f + ei;
    float Bv = 1.0f + ef;
    float G1 = eg + 1.0f;
    float G2 = eg - 1.0f;
    float AG = A * G1;
    float num = fmaf(c, AG, Bv * G2);
    float cn = num * rcp_f(Bv * AG);
    c = cn;
    float ec = exp2_f(cn * (2.0f * L2E));
    return (ec - 1.0f) * rcp_f((1.0f + eo) * (ec + 1.0f));
}

__device__ __forceinline__ unsigned ld_acq(const unsigned* p) {
    return __hip_atomic_load(p, __ATOMIC_ACQUIRE, __HIP_MEMORY_SCOPE_AGENT);
}
__device__ __forceinline__ unsigned ld_rlx(const unsigned* p) {
    return __hip_atomic_load(p, __ATOMIC_RELAXED, __HIP_MEMORY_SCOPE_AGENT);
}
__device__ __forceinline__ void st_rel(unsigned* p, unsigned v) {
    __hip_atomic_store(p, v, __ATOMIC_RELEASE, __HIP_MEMORY_SCOPE_AGENT);
}

__global__ void zero_flags(unsigned* f) { f[threadIdx.x] = 0u; }

// ============================================================================
// Layer-split producer/consumer kernel.
// Blocks [0,256): layer-0 producer for batch cols pair*16..+16.
// Blocks [256,512): layer-1 consumer + head for the same cols.
// h0(t) ships via a global ring (frag layout) with agent-scope flags.
// Wave 7 of each block is the comms wave; waves 0-6 carry 13 M-tiles.
// ============================================================================
__global__ __launch_bounds__(NTHR, 4) void lstm2_split(
    const float* __restrict__ x,      // [B, T]
    const float* __restrict__ W_ih0,  // [200, 1]
    const float* __restrict__ W_hh0,  // [200, 50]
    const float* __restrict__ b_ih0,  // [200]
    const float* __restrict__ b_hh0,  // [200]
    const float* __restrict__ W_ih1,  // [200, 50]
    const float* __restrict__ W_hh1,  // [200, 50]
    const float* __restrict__ b_ih1,  // [200]
    const float* __restrict__ b_hh1,  // [200]
    const float* __restrict__ W_fc,   // [4, 50]
    const float* __restrict__ b_fc,   // [4]
    float* __restrict__ out,          // [B, 4]
    char* __restrict__ ws, int R)
{
    __shared__ __align__(16) _Float16 hb[2][2][4][16][8];    // A: h0 dbuf | B: h1 dbuf (4KB)
    __shared__ __align__(16) _Float16 h0st[2][2][4][16][8];  // B: staged h0 (4KB)
    __shared__ float x_lds[BB][TT + 10];                     // A only (~33KB)
    __shared__ float h1f[64][BB + 1];                        // B only

    const int tid  = threadIdx.x;
    const int lane = tid & 63;
    const int w    = tid >> 6;
    const int col  = lane & 15;
    const int hi   = lane >> 4;
    const int am   = lane & 15;
    const int ak   = lane >> 4;
    const bool isA = (blockIdx.x < NPAIR);
    const int pair = isA ? blockIdx.x : (blockIdx.x - NPAIR);
    const int b0g  = pair * BB;
    unsigned* flagA = (unsigned*)ws + pair;          // steps published by producer
    unsigned* consB = (unsigned*)ws + NPAIR + pair;  // slots consumed by consumer
    char* ring = ws + 4096 + (size_t)pair * (size_t)R * 2048;

    // zero h double-buffer (pads must stay 0 forever)
    for (int i = tid; i < 1024; i += NTHR) ((unsigned*)hb)[i] = 0u;

    const int nt = (w < 6) ? 2 : (w == 6 ? 1 : 0);
    const int tiles0 = (w < 6) ? 2 * w : 12;
    const int tiles1 = (w < 6) ? 2 * w + 1 : 12;

    if (isA) {
        // ======================= PRODUCER: layer 0 =======================
        for (int it = 0; it < BB * TT / NTHR; ++it) {
            int idx = tid + it * NTHR;
            int bi = idx >> 9, ti = idx & (TT - 1);
            x_lds[bi][ti] = x[(size_t)(b0g + bi) * TT + ti];
        }
        if (tid < BB) x_lds[tid][TT] = 0.0f;

        half8 wa[2][2];
        f32x4 bv[2] = {};
        for (int tt = 0; tt < 2; ++tt) {
            wa[tt][0] = half8{}; wa[tt][1] = half8{};
            if (tt >= nt) continue;
            const int tile = tt ? tiles1 : tiles0;
            const int grow = tile * 16 + am;
            const int uu = grow >> 2, ty = grow & 3;
            const float rs = (ty == 2) ? 2.0f * L2E : -L2E;
            const bool ok = (uu < HH);
            const int gsrc = ty * HH + uu;
            for (int kt = 0; kt < 2; ++kt) {
                half8 a0 = {};
                for (int j = 0; j < 8; ++j) {
                    int k = kt * 32 + ((j >> 2) << 4) + ak * 4 + (j & 3);
                    if (ok) {
                        if (k < HH)       a0[j] = (_Float16)(rs * W_hh0[gsrc * HH + k]);
                        else if (k == 50) a0[j] = (_Float16)(rs * W_ih0[gsrc]);  // x slot
                    }
                }
                wa[tt][kt] = a0;
            }
            const int u = tile * 4 + hi;
            if (u < HH)
                for (int r = 0; r < 4; ++r) {
                    float s2 = (r == 2) ? 2.0f * L2E : -L2E;
                    int g = r * HH + u;
                    bv[tt][r] = s2 * (b_ih0[g] + b_hh0[g]);
                }
        }
        float c0[2] = {0.0f, 0.0f};
        __syncthreads();
        if (tid < 16) hb[0][1][0][tid][6] = (_Float16)x[(size_t)(b0g + tid) * TT];  // x_0 seed
        __syncthreads();

        int slotIdx = 0;
        unsigned cb = 0;
        int guard = 1 << 28;
        for (int s = 0; s <= TT + 1; ++s) {
            const int p = s & 1;
            if (w == 7) {
                // publish flag for last interval's shipped slot (release covers those stores)
                if (s >= 2 && lane == 0) st_rel(flagA, (unsigned)(s - 1));
                if (s >= 1 && s <= TT) {
                    // back-pressure (stale value is conservative; fresh spin only if needed)
                    if ((int)cb < s - R) {
                        do { cb = ld_rlx(consB); } while ((int)cb < s - R && --guard);
                    }
                    half8 f0 = *(const half8*)&hb[p][0][hi][col][0];
                    half8 f1 = *(const half8*)&hb[p][1][hi][col][0];
                    char* slot = ring + (size_t)slotIdx * 2048;
                    *(half8*)(slot + lane * 16)        = f0;
                    *(half8*)(slot + 1024 + lane * 16) = f1;
                    slotIdx = (slotIdx + 1 == R) ? 0 : slotIdx + 1;
                    cb = ld_rlx(consB);  // refresh for next interval (latency hidden)
                }
            } else if (s < TT) {
                half8 k0 = *(const half8*)&hb[p][0][hi][col][0];
                half8 k1 = *(const half8*)&hb[p][1][hi][col][0];
                f32x4 acc[2];
#pragma unroll
                for (int tt = 0; tt < 2; ++tt) if (tt < nt) {
                    f32x4 a = __builtin_amdgcn_mfma_f32_16x16x32_f16(wa[tt][0], k0, bv[tt], 0, 0, 0);
                    acc[tt] = __builtin_amdgcn_mfma_f32_16x16x32_f16(wa[tt][1], k1, a, 0, 0, 0);
                }
#pragma unroll
                for (int tt = 0; tt < 2; ++tt) if (tt < nt) {
                    const int u = (tt ? tiles1 : tiles0) * 4 + hi;
                    float h = cell_update(acc[tt], c0[tt]);
                    if (w == 6) {                        // tile 12 owns x slot (u==50)
                        float xv = x_lds[col][s + 1];
                        h = (u == 50) ? xv : h;
                    }
                    hb[p ^ 1][u >> 5][(u & 15) >> 2][col][(u & 3) | (((u >> 4) & 1) << 2)] = (_Float16)h;
                }
            }
            __syncthreads();
        }
    } else {
        // ======================= CONSUMER: layer 1 + head =======================
        half8 wi[2][2], wh[2][2];
        f32x4 bv[2] = {};
        for (int tt = 0; tt < 2; ++tt) {
            wi[tt][0] = half8{}; wi[tt][1] = half8{};
            wh[tt][0] = half8{}; wh[tt][1] = half8{};
            if (tt >= nt) continue;
            const int tile = tt ? tiles1 : tiles0;
            const int grow = tile * 16 + am;
            const int uu = grow >> 2, ty = grow & 3;
            const float rs = (ty == 2) ? 2.0f * L2E : -L2E;
            const bool ok = (uu < HH);
            const int gsrc = ty * HH + uu;
            for (int kt = 0; kt < 2; ++kt) {
                half8 a1 = {}, a2 = {};
                for (int j = 0; j < 8; ++j) {
                    int k = kt * 32 + ((j >> 2) << 4) + ak * 4 + (j & 3);
                    if (ok && k < HH) {
                        a1[j] = (_Float16)(rs * W_ih1[gsrc * HH + k]);
                        a2[j] = (_Float16)(rs * W_hh1[gsrc * HH + k]);
                    }
                }
                wi[tt][kt] = a1; wh[tt][kt] = a2;
            }
            const int u = tile * 4 + hi;
            if (u < HH)
                for (int r = 0; r < 4; ++r) {
                    float s2 = (r == 2) ? 2.0f * L2E : -L2E;
                    int g = r * HH + u;
                    bv[tt][r] = s2 * (b_ih1[g] + b_hh1[g]);
                }
        }
        float c1[2] = {0.0f, 0.0f};
        const f32x4 zz = {};
        __syncthreads();

        int slotIdx = 0;
        unsigned fl = 0;
        int guard = 1 << 28;
        if (w == 7) {   // prologue: stage h0(0)
            do { fl = ld_acq(flagA); } while (fl < 1u && --guard);
            half8 f0 = *(const half8*)(ring + lane * 16);
            half8 f1 = *(const half8*)(ring + 1024 + lane * 16);
            *(half8*)&h0st[0][0][hi][col][0] = f0;
            *(half8*)&h0st[0][1][hi][col][0] = f1;
            slotIdx = (1 == R) ? 0 : 1;
        }
        __syncthreads();

        for (int tau = 0; tau < TT; ++tau) {
            const int p = tau & 1;
            if (w == 7) {
                if (lane == 0) st_rel(consB, (unsigned)(tau + 1));  // release covers prior loads
                if (tau + 1 < TT) {
                    if (fl < (unsigned)(tau + 2)) {
                        do { fl = ld_acq(flagA); } while (fl < (unsigned)(tau + 2) && --guard);
                    }
                    char* slot = ring + (size_t)slotIdx * 2048;
                    half8 f0 = *(const half8*)(slot + lane * 16);
                    half8 f1 = *(const half8*)(slot + 1024 + lane * 16);
                    *(half8*)&h0st[(tau + 1) & 1][0][hi][col][0] = f0;
                    *(half8*)&h0st[(tau + 1) & 1][1][hi][col][0] = f1;
                    slotIdx = (slotIdx + 1 == R) ? 0 : slotIdx + 1;
                    fl = ld_acq(flagA);  // refresh (orders next interval's loads)
                }
            } else {
                half8 a0 = *(const half8*)&h0st[p][0][hi][col][0];   // h0(tau)
                half8 a1 = *(const half8*)&h0st[p][1][hi][col][0];
                half8 g0 = *(const half8*)&hb[p][0][hi][col][0];     // h1(tau-1)
                half8 g1 = *(const half8*)&hb[p][1][hi][col][0];
                f32x4 acc[2];
#pragma unroll
                for (int tt = 0; tt < 2; ++tt) if (tt < nt) {
                    f32x4 aI = __builtin_amdgcn_mfma_f32_16x16x32_f16(wi[tt][0], a0, bv[tt], 0, 0, 0);
                    aI       = __builtin_amdgcn_mfma_f32_16x16x32_f16(wi[tt][1], a1, aI, 0, 0, 0);
                    f32x4 aH = __builtin_amdgcn_mfma_f32_16x16x32_f16(wh[tt][0], g0, zz, 0, 0, 0);
                    aH       = __builtin_amdgcn_mfma_f32_16x16x32_f16(wh[tt][1], g1, aH, 0, 0, 0);
                    acc[tt] = aI + aH;
                }
#pragma unroll
                for (int tt = 0; tt < 2; ++tt) if (tt < nt) {
                    const int u = (tt ? tiles1 : tiles0) * 4 + hi;
                    float h = cell_update(acc[tt], c1[tt]);
                    hb[p ^ 1][u >> 5][(u & 15) >> 2][col][(u & 3) | (((u >> 4) & 1) << 2)] = (_Float16)h;
                    if (tau == TT - 1) h1f[u][col] = h;
                }
            }
            __syncthreads();
        }

        if (tid < BB * 4) {
            int b = tid >> 2, o = tid & 3;
            float accv = b_fc[o];
            for (int u2 = 0; u2 < HH; ++u2) accv = fmaf(W_fc[o * HH + u2], h1f[u2][b], accv);
            out[(size_t)(b0g + b) * 4 + o] = accv;
        }
    }
}

// ============================================================================
// Fallback (round-5 kernel) if workspace is too small for the ring.
// ============================================================================
__global__ __launch_bounds__(1024, 1) void lstm2_wide(
    const float* __restrict__ x, const float* __restrict__ W_ih0,
    const float* __restrict__ W_hh0, const float* __restrict__ b_ih0,
    const float* __restrict__ b_hh0, const float* __restrict__ W_ih1,
    const float* __restrict__ W_hh1, const float* __restrict__ b_ih1,
    const float* __restrict__ b_hh1, const float* __restrict__ W_fc,
    const float* __restrict__ b_fc, float* __restrict__ out)
{
    __shared__ __align__(16) _Float16 hb0[2][2][4][16][8];
    __shared__ __align__(16) _Float16 hb1[2][2][4][16][8];
    __shared__ float x_lds[BB][TT + 10];
    __shared__ float h1f[64][BB + 1];

    const int tid  = threadIdx.x;
    const int lane = tid & 63;
    const int wid  = tid >> 6;
    const int col  = lane & 15;
    const int hi   = lane >> 4;
    const int am   = lane & 15;
    const int ak   = lane >> 4;
    const int b0g  = blockIdx.x * BB;
    const bool active = (wid < 13);

    for (int it = 0; it < BB * TT / 1024; ++it) {
        int idx = tid + it * 1024;
        int bi = idx >> 9, ti = idx & (TT - 1);
        x_lds[bi][ti] = x[(size_t)(b0g + bi) * TT + ti];
    }
    if (tid < BB) x_lds[tid][TT] = 0.0f;
    for (int i = tid; i < 1024; i += 1024) {
        ((unsigned*)hb0)[i] = 0u; ((unsigned*)hb1)[i] = 0u;
    }

    half8 wA[2], wI[2], wH[2];
    f32x4 b0v = {}, b1v = {};
    {
        const int tile = wid;
        const int grow = tile * 16 + am;
        const int uu = grow >> 2, ty = grow & 3;
        const float rs = (ty == 2) ? 2.0f * L2E : -L2E;
        const bool ok = (uu < HH);
        const int gsrc = ty * HH + uu;
        for (int kt = 0; kt < 2; ++kt) {
            half8 a0 = {}, a1 = {}, a2 = {};
            for (int j = 0; j < 8; ++j) {
                int k = kt * 32 + ((j >> 2) << 4) + ak * 4 + (j & 3);
                if (ok) {
                    if (k < HH) {
                        a0[j] = (_Float16)(rs * W_hh0[gsrc * HH + k]);
                        a1[j] = (_Float16)(rs * W_ih1[gsrc * HH + k]);
                        a2[j] = (_Float16)(rs * W_hh1[gsrc * HH + k]);
                    } else if (k == 50) a0[j] = (_Float16)(rs * W_ih0[gsrc]);
                }
            }
            wA[kt] = a0; wI[kt] = a1; wH[kt] = a2;
        }
        const int u = tile * 4 + hi;
        if (u < HH)
            for (int r = 0; r < 4; ++r) {
                float s = (r == 2) ? 2.0f * L2E : -L2E;
                int g = r * HH + u;
                b0v[r] = s * (b_ih0[g] + b_hh0[g]);
                b1v[r] = s * (b_ih1[g] + b_hh1[g]);
            }
    }
    const int uown = wid * 4 + hi;
    const bool isx = (uown == 50);
    const int wkt = uown >> 5, whi = (uown & 15) >> 2;
    const int wsl = (uown & 3) | (((uown >> 4) & 1) << 2);
    float c0 = 0.0f, c1 = 0.0f;

    __syncthreads();
    if (tid < 16) hb0[0][1][0][tid][6] = (_Float16)x[(size_t)(b0g + tid) * TT];
    __syncthreads();

    auto step = [&](int s, int p) {
        if (s <= TT && active) {
            half8 h0k0 = *(const half8*)&hb0[p][0][hi][col][0];
            half8 h0k1 = *(const half8*)&hb0[p][1][hi][col][0];
            if (s < TT) {
                f32x4 a = __builtin_amdgcn_mfma_f32_16x16x32_f16(wA[0], h0k0, b0v, 0, 0, 0);
                a       = __builtin_amdgcn_mfma_f32_16x16x32_f16(wA[1], h0k1, a, 0, 0, 0);
                float h = cell_update(a, c0);
                if (wid == 12) { float xv = x_lds[col][s + 1]; h = isx ? xv : h; }
                hb0[p ^ 1][wkt][whi][col][wsl] = (_Float16)h;
            }
            if (s >= 1) {
                half8 h1k0 = *(const half8*)&hb1[p][0][hi][col][0];
                half8 h1k1 = *(const half8*)&hb1[p][1][hi][col][0];
                f32x4 aA = __builtin_amdgcn_mfma_f32_16x16x32_f16(wI[0], h0k0, b1v, 0, 0, 0);
                aA       = __builtin_amdgcn_mfma_f32_16x16x32_f16(wI[1], h0k1, aA, 0, 0, 0);
                f32x4 aB = {};
                aB       = __builtin_amdgcn_mfma_f32_16x16x32_f16(wH[0], h1k0, aB, 0, 0, 0);
                aB       = __builtin_amdgcn_mfma_f32_16x16x32_f16(wH[1], h1k1, aB, 0, 0, 0);
                f32x4 a  = aA + aB;
                float h = cell_update(a, c1);
                hb1[p ^ 1][wkt][whi][col][wsl] = (_Float16)h;
                if (s == TT) h1f[uown][col] = h;
            }
        }
        __syncthreads();
    };
    for (int s = 0; s < TT + 2; s += 2) { step(s, 0); step(s + 1, 1); }

    if (tid < BB * 4) {
        int b = tid >> 2, o = tid & 3;
        float acc = b_fc[o];
        for (int u = 0; u < HH; ++u) acc = fmaf(W_fc[o * HH + u], h1f[u][b], acc);
        out[(size_t)(b0g + b) * 4 + o] = acc;
    }
}

extern "C" void kernel_launch(void* const* d_in, const int* in_sizes, int n_in,
                              void* d_out, int out_size, void* d_ws, size_t ws_size,
                              hipStream_t stream) {
    const float* x     = (const float*)d_in[0];
    const float* W_ih0 = (const float*)d_in[1];
    const float* W_hh0 = (const float*)d_in[2];
    const float* b_ih0 = (const float*)d_in[3];
    const float* b_hh0 = (const float*)d_in[4];
    const float* W_ih1 = (const float*)d_in[5];
    const float* W_hh1 = (const float*)d_in[6];
    const float* b_ih1 = (const float*)d_in[7];
    const float* b_hh1 = (const float*)d_in[8];
    const float* W_fc  = (const float*)d_in[9];
    const float* b_fc  = (const float*)d_in[10];
    float* out = (float*)d_out;

    const size_t minws = 4096 + (size_t)NPAIR * 2 * 2048;   // R >= 2
    if (ws_size >= minws) {
        int R = (int)((ws_size - 4096) / ((size_t)NPAIR * 2048));
        if (R > 16) R = 16;
        zero_flags<<<1, 512, 0, stream>>>((unsigned*)d_ws);
        lstm2_split<<<dim3(2 * NPAIR), dim3(NTHR), 0, stream>>>(
            x, W_ih0, W_hh0, b_ih0, b_hh0, W_ih1, W_hh1, b_ih1, b_hh1,
            W_fc, b_fc, out, (char*)d_ws, R);
    } else {
        lstm2_wide<<<dim3(256), dim3(1024), 0, stream>>>(
            x, W_ih0, W_hh0, b_ih0, b_hh0, W_ih1, W_hh1, b_ih1, b_hh1,
            W_fc, b_fc, out);
    }
}

// Round 7
// 569.409 us; speedup vs baseline: 8.6279x; 8.6279x over previous
//
#include <hip/hip_runtime.h>

typedef _Float16 half8 __attribute__((ext_vector_type(8)));
typedef float f32x4 __attribute__((ext_vector_type(4)));

#define TT   512
#define BB   16      // batch cols per block
#define HH   50
#define NW   13      // 13 waves, 1 M-tile each (200 padded gate rows -> 13 tiles)
#define NTHR (NW * 64)
#define L2E  1.44269504088896340736f

__device__ __forceinline__ float rcp_f(float x) { return __builtin_amdgcn_rcpf(x); }
__device__ __forceinline__ float exp2_f(float x) { return __builtin_amdgcn_exp2f(x); }

// Fused LSTM cell update, 7 trans ops (5 exp2 + 2 rcp).
// Preacts prescaled: i,f,o rows by -log2e, g rows by +2log2e.
// c' = [c*(1+ei)(eg+1) + (1+ef)(eg-1)] / [(1+ef)(1+ei)(eg+1)]
// h  = (ec-1) / [(1+eo)(ec+1)],  ec = 2^{2*log2e*c'}
__device__ __forceinline__ float cell_update(f32x4 a, float& c) {
    float ei = exp2_f(a[0]);
    float ef = exp2_f(a[1]);
    float eg = exp2_f(a[2]);
    float eo = exp2_f(a[3]);
    float A  = 1.0f + ei;
    float Bv = 1.0f + ef;
    float G1 = eg + 1.0f;
    float G2 = eg - 1.0f;
    float AG = A * G1;
    float num = fmaf(c, AG, Bv * G2);
    float cn = num * rcp_f(Bv * AG);
    c = cn;
    float ec = exp2_f(cn * (2.0f * L2E));
    return (ec - 1.0f) * rcp_f((1.0f + eo) * (ec + 1.0f));
}

__device__ __forceinline__ void spin_ge(int* ctr, int target) {
    int guard = 1 << 22;   // bounded: ~0.25 s worst case, then proceed (absmax catches)
    while (__hip_atomic_load(ctr, __ATOMIC_ACQUIRE, __HIP_MEMORY_SCOPE_WORKGROUP) < target) {
        if (--guard == 0) break;
    }
}

__global__ __launch_bounds__(NTHR, 1) void lstm2_async(
    const float* __restrict__ x,      // [B, T]
    const float* __restrict__ W_ih0,  // [200, 1]
    const float* __restrict__ W_hh0,  // [200, 50]
    const float* __restrict__ b_ih0,  // [200]
    const float* __restrict__ b_hh0,  // [200]
    const float* __restrict__ W_ih1,  // [200, 50]
    const float* __restrict__ W_hh1,  // [200, 50]
    const float* __restrict__ b_ih1,  // [200]
    const float* __restrict__ b_hh1,  // [200]
    const float* __restrict__ W_fc,   // [4, 50]
    const float* __restrict__ b_fc,   // [4]
    float* __restrict__ out)          // [B, 4]
{
    // h exchange: [parity][kt][hi][col][8 f16] -> one lane-linear b128 per frag
    __shared__ __align__(16) _Float16 hb0[2][2][4][16][8];   // 4 KB
    __shared__ __align__(16) _Float16 hb1[2][2][4][16][8];   // 4 KB
    __shared__ float x_lds[BB][TT + 10];                     // ~33 KB
    __shared__ float h1f[64][BB + 1];                        // final h1 (fp32)
    __shared__ int prodc[2], consc[2];                       // epoch counters

    const int tid  = threadIdx.x;
    const int lane = tid & 63;
    const int wid  = tid >> 6;        // 13 waves; tile = wid
    const int col  = lane & 15;       // batch col
    const int hi   = lane >> 4;
    const int am   = lane & 15;       // A row within tile
    const int ak   = lane >> 4;       // A k-group
    const int b0g  = blockIdx.x * BB;

    // ---- stage x; zero t=TT pad column ----
    for (int i = tid; i < BB * TT; i += NTHR) {
        int bi = i >> 9, ti = i & (TT - 1);
        x_lds[bi][ti] = x[(size_t)(b0g + bi) * TT + ti];
    }
    if (tid < BB) x_lds[tid][TT] = 0.0f;
    // ---- zero both parities of both h buffers; init counters ----
    for (int i = tid; i < 1024; i += NTHR) {
        ((unsigned*)hb0)[i] = 0u;
        ((unsigned*)hb1)[i] = 0u;
    }
    if (tid < 2) { prodc[tid] = 0; consc[tid] = 0; }

    // ---- stationary A-frags (f16), gate rows reordered to 4u+type.
    //      Row scales: i,f,o -> -log2e ; g -> +2log2e. k=50 of W_hh0 carries W_ih0.
    half8 wA[2], wI[2], wH[2];
    f32x4 b0v = {}, b1v = {};
    {
        const int tile = wid;
        const int grow = tile * 16 + am;
        const int uu = grow >> 2, ty = grow & 3;
        const float rs = (ty == 2) ? 2.0f * L2E : -L2E;
        const bool ok = (uu < HH);
        const int gsrc = ty * HH + uu;
        for (int kt = 0; kt < 2; ++kt) {
            half8 a0 = {}, a1 = {}, a2 = {};
            for (int j = 0; j < 8; ++j) {
                int k = kt * 32 + ((j >> 2) << 4) + ak * 4 + (j & 3);
                if (ok) {
                    if (k < HH) {
                        a0[j] = (_Float16)(rs * W_hh0[gsrc * HH + k]);
                        a1[j] = (_Float16)(rs * W_ih1[gsrc * HH + k]);
                        a2[j] = (_Float16)(rs * W_hh1[gsrc * HH + k]);
                    } else if (k == 50) {
                        a0[j] = (_Float16)(rs * W_ih0[gsrc]);   // x rides h0 slot 50
                    }
                }
            }
            wA[kt] = a0; wI[kt] = a1; wH[kt] = a2;
        }
        const int u = tile * 4 + hi;
        if (u < HH)
            for (int r = 0; r < 4; ++r) {
                float s = (r == 2) ? 2.0f * L2E : -L2E;
                int g = r * HH + u;
                b0v[r] = s * (b_ih0[g] + b_hh0[g]);
                b1v[r] = s * (b_ih1[g] + b_hh1[g]);
            }
    }
    const int uown = wid * 4 + hi;
    const bool isx = (uown == 50);
    const int wkt = uown >> 5, whi = (uown & 15) >> 2;
    const int wsl = (uown & 3) | (((uown >> 4) & 1) << 2);
    float c0 = 0.0f, c1 = 0.0f;

    __syncthreads();
    if (tid < 16) hb0[0][1][0][tid][6] = (_Float16)x[(size_t)(b0g + tid) * TT];  // x_0 seed
    __syncthreads();

    // ---- barrier-free pipelined steps: step s = L0(s) || L1(s-1).
    //      All reads from parity p = s&1, all writes to p^1.
    int need_prod[2] = {0, 0}, need_cons[2] = {0, 0};

    for (int s = 0; s <= TT; ++s) {
        const int p = s & 1;
        const int q = p ^ 1;

        // wait until all step-(s-1) writes to parity p have landed
        if (need_prod[p] > 0) spin_ge(&prodc[p], need_prod[p]);

        half8 h0k0 = *(const half8*)&hb0[p][0][hi][col][0];
        half8 h0k1 = *(const half8*)&hb0[p][1][hi][col][0];
        half8 h1k0 = *(const half8*)&hb1[p][0][hi][col][0];
        half8 h1k1 = *(const half8*)&hb1[p][1][hi][col][0];

        float hv0 = 0.0f, hv1 = 0.0f;
        if (s < TT) {   // layer 0, timestep s
            f32x4 a = __builtin_amdgcn_mfma_f32_16x16x32_f16(wA[0], h0k0, b0v, 0, 0, 0);
            a       = __builtin_amdgcn_mfma_f32_16x16x32_f16(wA[1], h0k1, a, 0, 0, 0);
            hv0 = cell_update(a, c0);
            if (wid == 12) {                     // tile 12 owns the x slot (u==50)
                float xv = x_lds[col][s + 1];
                hv0 = isx ? xv : hv0;
            }
        }
        if (s >= 1) {   // layer 1, timestep s-1 (two independent 2-deep chains)
            f32x4 aA = __builtin_amdgcn_mfma_f32_16x16x32_f16(wI[0], h0k0, b1v, 0, 0, 0);
            aA       = __builtin_amdgcn_mfma_f32_16x16x32_f16(wI[1], h0k1, aA, 0, 0, 0);
            f32x4 aB = {};
            aB       = __builtin_amdgcn_mfma_f32_16x16x32_f16(wH[0], h1k0, aB, 0, 0, 0);
            aB       = __builtin_amdgcn_mfma_f32_16x16x32_f16(wH[1], h1k1, aB, 0, 0, 0);
            f32x4 a  = aA + aB;
            hv1 = cell_update(a, c1);
        }

        // signal: this wave's parity-p reads are consumed (release orders the reads)
        if (lane == 0)
            __hip_atomic_fetch_add(&consc[p], 1, __ATOMIC_RELEASE, __HIP_MEMORY_SCOPE_WORKGROUP);

        // before overwriting parity q: all step-(s-1) readers of q must be done
        if (need_cons[q] > 0) spin_ge(&consc[q], need_cons[q]);

        if (s < TT) hb0[q][wkt][whi][col][wsl] = (_Float16)hv0;
        if (s >= 1) {
            hb1[q][wkt][whi][col][wsl] = (_Float16)hv1;
            if (s == TT) h1f[uown][col] = hv1;   // final h1(T-1), fp32
        }

        // signal: this wave's parity-q writes are visible (release orders the writes)
        if (lane == 0)
            __hip_atomic_fetch_add(&prodc[q], 1, __ATOMIC_RELEASE, __HIP_MEMORY_SCOPE_WORKGROUP);

        need_prod[q] += NW;   // step s+1 (parity q) must see these writes
        need_cons[p] += NW;   // step s+1 writes parity p -> must see our reads done
    }

    __syncthreads();

    // ---- linear head: out[b][o] = h1[b][:50] . W_fc[o][:] + b_fc[o] ----
    if (tid < BB * 4) {
        int b = tid >> 2, o = tid & 3;
        float acc = b_fc[o];
        for (int u = 0; u < HH; ++u) acc = fmaf(W_fc[o * HH + u], h1f[u][b], acc);
        out[(size_t)(b0g + b) * 4 + o] = acc;
    }
}

extern "C" void kernel_launch(void* const* d_in, const int* in_sizes, int n_in,
                              void* d_out, int out_size, void* d_ws, size_t ws_size,
                              hipStream_t stream) {
    const float* x     = (const float*)d_in[0];
    const float* W_ih0 = (const float*)d_in[1];
    const float* W_hh0 = (const float*)d_in[2];
    const float* b_ih0 = (const float*)d_in[3];
    const float* b_hh0 = (const float*)d_in[4];
    const float* W_ih1 = (const float*)d_in[5];
    const float* W_hh1 = (const float*)d_in[6];
    const float* b_ih1 = (const float*)d_in[7];
    const float* b_hh1 = (const float*)d_in[8];
    const float* W_fc  = (const float*)d_in[9];
    const float* b_fc  = (const float*)d_in[10];
    float* out = (float*)d_out;

    const int B = 4096;
    dim3 grid(B / BB), block(NTHR);
    lstm2_async<<<grid, block, 0, stream>>>(
        x, W_ih0, W_hh0, b_ih0, b_hh0, W_ih1, W_hh1, b_ih1, b_hh1, W_fc, b_fc, out);
}

// Round 8
// 319.151 us; speedup vs baseline: 15.3934x; 1.7841x over previous
//
#include <hip/hip_runtime.h>

typedef _Float16 half8 __attribute__((ext_vector_type(8)));
typedef float f32x4 __attribute__((ext_vector_type(4)));
typedef float f32x2 __attribute__((ext_vector_type(2)));

#define TT   512
#define BB   16      // batch cols per block
#define HH   50
#define NW   13      // 13 waves, 1 M-tile each (208 padded gate rows)
#define NTHR (NW * 64)
#define L2E  1.44269504088896340736f

__device__ __forceinline__ float rcp_f(float x) { return __builtin_amdgcn_rcpf(x); }
__device__ __forceinline__ float exp2_f(float x) { return __builtin_amdgcn_exp2f(x); }

// Scalar fused LSTM cell update (5 exp2 + 2 rcp).
// Preacts prescaled: i,f,o rows by -log2e, g rows by +2log2e.
__device__ __forceinline__ float cell_update(f32x4 a, float& c) {
    float ei = exp2_f(a[0]);
    float ef = exp2_f(a[1]);
    float eg = exp2_f(a[2]);
    float eo = exp2_f(a[3]);
    float A  = 1.0f + ei;
    float Bv = 1.0f + ef;
    float G1 = eg + 1.0f;
    float G2 = eg - 1.0f;
    float AG = A * G1;
    float num = fmaf(c, AG, Bv * G2);
    float cn = num * rcp_f(Bv * AG);
    c = cn;
    float ec = exp2_f(cn * (2.0f * L2E));
    return (ec - 1.0f) * rcp_f((1.0f + eo) * (ec + 1.0f));
}

// Packed dual-layer update: both layers' cell updates as f32x2 (v_pk_* VALU).
__device__ __forceinline__ void cell_update2(const f32x4& a0, const f32x4& a1,
                                             float& c0, float& c1,
                                             float& hv0, float& hv1) {
    f32x2 ei = {exp2_f(a0[0]), exp2_f(a1[0])};
    f32x2 ef = {exp2_f(a0[1]), exp2_f(a1[1])};
    f32x2 eg = {exp2_f(a0[2]), exp2_f(a1[2])};
    f32x2 eo = {exp2_f(a0[3]), exp2_f(a1[3])};
    const f32x2 one = {1.0f, 1.0f};
    f32x2 A  = one + ei;
    f32x2 Bv = one + ef;
    f32x2 G1 = one + eg;
    f32x2 G2 = eg - one;
    f32x2 AG = A * G1;
    f32x2 cc = {c0, c1};
    f32x2 num = cc * AG + Bv * G2;
    f32x2 den = Bv * AG;
    f32x2 r   = {rcp_f(den[0]), rcp_f(den[1])};
    f32x2 cn  = num * r;
    c0 = cn[0]; c1 = cn[1];
    f32x2 ec = {exp2_f(cn[0] * (2.0f * L2E)), exp2_f(cn[1] * (2.0f * L2E))};
    f32x2 hn = ec - one;
    f32x2 hd = (one + eo) * (ec + one);
    f32x2 rh = {rcp_f(hd[0]), rcp_f(hd[1])};
    f32x2 hh = hn * rh;
    hv0 = hh[0]; hv1 = hh[1];
}

__global__ __launch_bounds__(NTHR, 1) void lstm2_pk(
    const float* __restrict__ x,      // [B, T]
    const float* __restrict__ W_ih0,  // [200, 1]
    const float* __restrict__ W_hh0,  // [200, 50]
    const float* __restrict__ b_ih0,  // [200]
    const float* __restrict__ b_hh0,  // [200]
    const float* __restrict__ W_ih1,  // [200, 50]
    const float* __restrict__ W_hh1,  // [200, 50]
    const float* __restrict__ b_ih1,  // [200]
    const float* __restrict__ b_hh1,  // [200]
    const float* __restrict__ W_fc,   // [4, 50]
    const float* __restrict__ b_fc,   // [4]
    float* __restrict__ out)          // [B, 4]
{
    // h exchange: [parity][kt][hi][col][8 f16] -> one lane-linear b128 per frag
    __shared__ __align__(16) _Float16 hb0[2][2][4][16][8];   // 4 KB
    __shared__ __align__(16) _Float16 hb1[2][2][4][16][8];   // 4 KB
    __shared__ float x_lds[BB][TT + 10];                     // ~33 KB
    __shared__ float h1f[64][BB + 1];                        // final h1 (fp32)

    const int tid  = threadIdx.x;
    const int lane = tid & 63;
    const int wid  = tid >> 6;        // 13 waves; tile = wid
    const int col  = lane & 15;       // batch col
    const int hi   = lane >> 4;
    const int am   = lane & 15;       // A row within tile
    const int ak   = lane >> 4;       // A k-group
    const int b0g  = blockIdx.x * BB;

    // ---- stage x; zero t=TT pad column ----
    for (int i = tid; i < BB * TT; i += NTHR) {
        int bi = i >> 9, ti = i & (TT - 1);
        x_lds[bi][ti] = x[(size_t)(b0g + bi) * TT + ti];
    }
    if (tid < BB) x_lds[tid][TT] = 0.0f;
    // ---- zero both parities of both h buffers ----
    for (int i = tid; i < 1024; i += NTHR) {
        ((unsigned*)hb0)[i] = 0u;
        ((unsigned*)hb1)[i] = 0u;
    }

    // ---- stationary A-frags (f16), gate rows reordered to 4u+type.
    //      Row scales: i,f,o -> -log2e ; g -> +2log2e. k=50 of W_hh0 carries W_ih0.
    half8 wA[2], wI[2], wH[2];
    f32x4 b0v = {}, b1v = {};
    {
        const int tile = wid;
        const int grow = tile * 16 + am;
        const int uu = grow >> 2, ty = grow & 3;
        const float rs = (ty == 2) ? 2.0f * L2E : -L2E;
        const bool ok = (uu < HH);
        const int gsrc = ty * HH + uu;
        for (int kt = 0; kt < 2; ++kt) {
            half8 a0 = {}, a1 = {}, a2 = {};
            for (int j = 0; j < 8; ++j) {
                int k = kt * 32 + ((j >> 2) << 4) + ak * 4 + (j & 3);
                if (ok) {
                    if (k < HH) {
                        a0[j] = (_Float16)(rs * W_hh0[gsrc * HH + k]);
                        a1[j] = (_Float16)(rs * W_ih1[gsrc * HH + k]);
                        a2[j] = (_Float16)(rs * W_hh1[gsrc * HH + k]);
                    } else if (k == 50) {
                        a0[j] = (_Float16)(rs * W_ih0[gsrc]);   // x rides h0 slot 50
                    }
                }
            }
            wA[kt] = a0; wI[kt] = a1; wH[kt] = a2;
        }
        const int u = tile * 4 + hi;
        if (u < HH)
            for (int r = 0; r < 4; ++r) {
                float s = (r == 2) ? 2.0f * L2E : -L2E;
                int g = r * HH + u;
                b0v[r] = s * (b_ih0[g] + b_hh0[g]);
                b1v[r] = s * (b_ih1[g] + b_hh1[g]);
            }
    }
    const int uown = wid * 4 + hi;
    const bool isx = (uown == 50);
    const int wkt = uown >> 5, whi = (uown & 15) >> 2;
    const int wsl = (uown & 3) | (((uown >> 4) & 1) << 2);
    float c0 = 0.0f, c1 = 0.0f;

    __syncthreads();
    if (tid < 16) hb0[0][1][0][tid][6] = (_Float16)x[(size_t)(b0g + tid) * TT];  // x_0 seed
    __syncthreads();

    // ---- full interior step: L0(s) || L1(s-1), reads parity p, writes p^1 ----
    auto full_step = [&](int s, int p) {
        const int q = p ^ 1;
        half8 h0k0 = *(const half8*)&hb0[p][0][hi][col][0];
        half8 h0k1 = *(const half8*)&hb0[p][1][hi][col][0];
        half8 h1k0 = *(const half8*)&hb1[p][0][hi][col][0];
        half8 h1k1 = *(const half8*)&hb1[p][1][hi][col][0];
        float xv = (wid == 12) ? x_lds[col][s + 1] : 0.0f;   // issue early

        f32x4 a0 = __builtin_amdgcn_mfma_f32_16x16x32_f16(wA[0], h0k0, b0v, 0, 0, 0);
        a0       = __builtin_amdgcn_mfma_f32_16x16x32_f16(wA[1], h0k1, a0, 0, 0, 0);
        f32x4 aA = __builtin_amdgcn_mfma_f32_16x16x32_f16(wI[0], h0k0, b1v, 0, 0, 0);
        aA       = __builtin_amdgcn_mfma_f32_16x16x32_f16(wI[1], h0k1, aA, 0, 0, 0);
        f32x4 aB = {};
        aB       = __builtin_amdgcn_mfma_f32_16x16x32_f16(wH[0], h1k0, aB, 0, 0, 0);
        aB       = __builtin_amdgcn_mfma_f32_16x16x32_f16(wH[1], h1k1, aB, 0, 0, 0);
        f32x4 a1 = aA + aB;

        float hv0, hv1;
        cell_update2(a0, a1, c0, c1, hv0, hv1);
        if (wid == 12) hv0 = isx ? xv : hv0;                 // slot 50 <- x_{s+1}
        hb0[q][wkt][whi][col][wsl] = (_Float16)hv0;
        hb1[q][wkt][whi][col][wsl] = (_Float16)hv1;
        __syncthreads();
    };

    // ---- s = 0 (p=0): L0 only ----
    {
        half8 h0k0 = *(const half8*)&hb0[0][0][hi][col][0];
        half8 h0k1 = *(const half8*)&hb0[0][1][hi][col][0];
        f32x4 a = __builtin_amdgcn_mfma_f32_16x16x32_f16(wA[0], h0k0, b0v, 0, 0, 0);
        a       = __builtin_amdgcn_mfma_f32_16x16x32_f16(wA[1], h0k1, a, 0, 0, 0);
        float h = cell_update(a, c0);
        if (wid == 12) { float xv = x_lds[col][1]; h = isx ? xv : h; }
        hb0[1][wkt][whi][col][wsl] = (_Float16)h;
        __syncthreads();
    }
    // ---- interior s = 1..510, unrolled by 2 with literal parity ----
    for (int s = 1; s <= TT - 3; s += 2) {
        full_step(s, 1);
        full_step(s + 1, 0);
    }
    full_step(TT - 1, 1);   // s = 511
    // ---- s = 512 (p=0): L1 only, stash final h1 ----
    {
        half8 h0k0 = *(const half8*)&hb0[0][0][hi][col][0];
        half8 h0k1 = *(const half8*)&hb0[0][1][hi][col][0];
        half8 h1k0 = *(const half8*)&hb1[0][0][hi][col][0];
        half8 h1k1 = *(const half8*)&hb1[0][1][hi][col][0];
        f32x4 aA = __builtin_amdgcn_mfma_f32_16x16x32_f16(wI[0], h0k0, b1v, 0, 0, 0);
        aA       = __builtin_amdgcn_mfma_f32_16x16x32_f16(wI[1], h0k1, aA, 0, 0, 0);
        f32x4 aB = {};
        aB       = __builtin_amdgcn_mfma_f32_16x16x32_f16(wH[0], h1k0, aB, 0, 0, 0);
        aB       = __builtin_amdgcn_mfma_f32_16x16x32_f16(wH[1], h1k1, aB, 0, 0, 0);
        f32x4 a  = aA + aB;
        float h = cell_update(a, c1);
        h1f[uown][col] = h;
        __syncthreads();
    }

    // ---- linear head: out[b][o] = h1[b][:50] . W_fc[o][:] + b_fc[o] ----
    if (tid < BB * 4) {
        int b = tid >> 2, o = tid & 3;
        float acc = b_fc[o];
        for (int u = 0; u < HH; ++u) acc = fmaf(W_fc[o * HH + u], h1f[u][b], acc);
        out[(size_t)(b0g + b) * 4 + o] = acc;
    }
}

extern "C" void kernel_launch(void* const* d_in, const int* in_sizes, int n_in,
                              void* d_out, int out_size, void* d_ws, size_t ws_size,
                              hipStream_t stream) {
    const float* x     = (const float*)d_in[0];
    const float* W_ih0 = (const float*)d_in[1];
    const float* W_hh0 = (const float*)d_in[2];
    const float* b_ih0 = (const float*)d_in[3];
    const float* b_hh0 = (const float*)d_in[4];
    const float* W_ih1 = (const float*)d_in[5];
    const float* W_hh1 = (const float*)d_in[6];
    const float* b_ih1 = (const float*)d_in[7];
    const float* b_hh1 = (const float*)d_in[8];
    const float* W_fc  = (const float*)d_in[9];
    const float* b_fc  = (const float*)d_in[10];
    float* out = (float*)d_out;

    const int B = 4096;
    dim3 grid(B / BB), block(NTHR);
    lstm2_pk<<<grid, block, 0, stream>>>(
        x, W_ih0, W_hh0, b_ih0, b_hh0, W_ih1, W_hh1, b_ih1, b_hh1, W_fc, b_fc, out);
}